// Round 3
// baseline (93.064 us; speedup 1.0000x reference)
//
#include <hip/hip_runtime.h>
#include <hip/hip_bf16.h>

#define NROW 8192
#define DIM  128
#define JSPLIT 8
#define BIGF 1e30f

typedef __attribute__((ext_vector_type(8))) short bf16x8;
typedef __attribute__((ext_vector_type(4))) float f32x4;

// ws layout:
//   [0, 2 MB)        xbT  : fragment-major bf16. chunk c = (tile*4 + ks)*4 + quad,
//                           chunk holds 16 lanes x 16 B: rows tile*16+l15, cols ks*32+quad*8..+7
//   [+2 MB, +64 KB)  meta : uint2 { float bits sq[j], lbl[j] }
//   [+..., +32 KB)   posb : u32 (d^2 bits, atomicMax)
//   [+..., +32 KB)   negb : u32 (d^2 bits, atomicMin)

__device__ __forceinline__ unsigned short f2bf(float f) {
    unsigned u = __float_as_uint(f);
    unsigned r = (u + 0x7fffu + ((u >> 16) & 1u)) >> 16;   // RNE
    return (unsigned short)r;
}

__global__ __launch_bounds__(256) void prep_kernel(const float* __restrict__ x,
                                                   const int* __restrict__ lbl,
                                                   unsigned short* __restrict__ xbT,
                                                   uint2* __restrict__ meta,
                                                   unsigned* __restrict__ posb,
                                                   unsigned* __restrict__ negb,
                                                   float* __restrict__ out) {
    int gtid = blockIdx.x * 256 + threadIdx.x;
    if (gtid < NROW) {
        posb[gtid] = 0u;                       // 0.0f
        negb[gtid] = __float_as_uint(BIGF);
    }
    if (gtid == 0) out[0] = 0.0f;

    // one wave per 16-row tile: grid 128*256/64 = 512 waves = 512 tiles
    int wave = gtid >> 6;
    int lane = threadIdx.x & 63;
    int q = lane >> 4, l = lane & 15;
    int row = wave * 16 + l;
    const float* xr = x + (size_t)row * DIM + q * 8;

    float s = 0.0f;
    #pragma unroll
    for (int ks = 0; ks < 4; ks++) {
        float4 a = *(const float4*)(xr + ks * 32);
        float4 b = *(const float4*)(xr + ks * 32 + 4);
        s += a.x * a.x + a.y * a.y + a.z * a.z + a.w * a.w;
        s += b.x * b.x + b.y * b.y + b.z * b.z + b.w * b.w;
        uint4 u;
        u.x = (unsigned)f2bf(a.x) | ((unsigned)f2bf(a.y) << 16);
        u.y = (unsigned)f2bf(a.z) | ((unsigned)f2bf(a.w) << 16);
        u.z = (unsigned)f2bf(b.x) | ((unsigned)f2bf(b.y) << 16);
        u.w = (unsigned)f2bf(b.z) | ((unsigned)f2bf(b.w) << 16);
        *(uint4*)(xbT + (size_t)wave * 2048 + ks * 512 + lane * 8) = u;
    }
    // full row sq-norm: lanes (q=0..3, same l) each hold a quarter
    s += __shfl_xor(s, 16);
    s += __shfl_xor(s, 32);
    if (q == 0) {
        uint2 mv;
        mv.x = __float_as_uint(s);
        mv.y = (unsigned)lbl[row];
        meta[row] = mv;
    }
}

__global__ __launch_bounds__(256, 2) void tri_mfma(const unsigned short* __restrict__ xbT,
                                                   const uint2* __restrict__ meta,
                                                   unsigned* __restrict__ posb,
                                                   unsigned* __restrict__ negb) {
    const int bid  = blockIdx.x;
    const int rb   = bid >> 3;           // 0..63
    const int jq   = bid & 7;            // 0..7
    const int i0   = rb * 128;
    const int t    = threadIdx.x;
    const int lane = t & 63;
    const int w    = t >> 6;
    const int wrow = (w >> 1) * 64;
    const int wcol = (w & 1) * 64;
    const int quad = lane >> 4;
    const int l15  = lane & 15;

    // ---- A fragments: held in registers for the whole kernel ----
    bf16x8 A[4][4];
    {
        const int tbase = (i0 + wrow) >> 4;
        #pragma unroll
        for (int ti = 0; ti < 4; ti++)
            #pragma unroll
            for (int ks = 0; ks < 4; ks++)
                A[ti][ks] = *(const bf16x8*)(xbT + ((size_t)(tbase + ti) * 2048 + ks * 512 + lane * 8));
    }

    // row metadata: rows i0 + wrow + ti*16 + quad*4 + r
    float sqi[4][4]; int lbli[4][4];
    #pragma unroll
    for (int ti = 0; ti < 4; ti++) {
        int rbase = i0 + wrow + ti * 16 + quad * 4;
        uint4 m01 = *(const uint4*)(meta + rbase);
        uint4 m23 = *(const uint4*)(meta + rbase + 2);
        sqi[ti][0] = __uint_as_float(m01.x); lbli[ti][0] = (int)m01.y;
        sqi[ti][1] = __uint_as_float(m01.z); lbli[ti][1] = (int)m01.w;
        sqi[ti][2] = __uint_as_float(m23.x); lbli[ti][2] = (int)m23.y;
        sqi[ti][3] = __uint_as_float(m23.z); lbli[ti][3] = (int)m23.w;
    }

    // running s = (sq_j - 2*dot) extrema; d^2 = sq_i + s at the end
    float posm[4][4], negm[4][4];
    #pragma unroll
    for (int ti = 0; ti < 4; ti++)
        #pragma unroll
        for (int r = 0; r < 4; r++) { posm[ti][r] = -BIGF; negm[ti][r] = BIGF; }

    const int jbase = jq * (NROW / JSPLIT);
    const int dr    = l15 - quad * 4;        // diag element when dr == r (and ti == tj)

    #pragma unroll 1
    for (int jt = 0; jt < (NROW / JSPLIT) / 128; jt++) {
        const int j0 = jbase + jt * 128;
        const int tb = (j0 + wcol) >> 4;

        // B fragments straight from L2 (coalesced 1 KB per inst)
        bf16x8 Bv[4][4];
        #pragma unroll
        for (int tj = 0; tj < 4; tj++)
            #pragma unroll
            for (int ks = 0; ks < 4; ks++)
                Bv[tj][ks] = *(const bf16x8*)(xbT + ((size_t)(tb + tj) * 2048 + ks * 512 + lane * 8));

        // column metadata
        float sqj[4]; int lblj[4];
        #pragma unroll
        for (int tj = 0; tj < 4; tj++) {
            uint2 mv = meta[j0 + wcol + tj * 16 + l15];
            sqj[tj]  = __uint_as_float(mv.x);
            lblj[tj] = (int)mv.y;
        }

        f32x4 acc[4][4];
        #pragma unroll
        for (int ti = 0; ti < 4; ti++)
            #pragma unroll
            for (int tj = 0; tj < 4; tj++) acc[ti][tj] = (f32x4){0.f, 0.f, 0.f, 0.f};

        #pragma unroll
        for (int ks = 0; ks < 4; ks++)
            #pragma unroll
            for (int ti = 0; ti < 4; ti++)
                #pragma unroll
                for (int tj = 0; tj < 4; tj++)
                    acc[ti][tj] = __builtin_amdgcn_mfma_f32_16x16x32_bf16(A[ti][ks], Bv[tj][ks], acc[ti][tj], 0, 0, 0);

        const bool diag = (i0 + wrow) == (j0 + wcol);   // wave-uniform
        if (!diag) {
            #pragma unroll
            for (int ti = 0; ti < 4; ti++)
                #pragma unroll
                for (int tj = 0; tj < 4; tj++)
                    #pragma unroll
                    for (int r = 0; r < 4; r++) {
                        float s = fmaf(-2.0f, acc[ti][tj][r], sqj[tj]);
                        bool same = (lbli[ti][r] == lblj[tj]);
                        posm[ti][r] = fmaxf(posm[ti][r], same ? s : -BIGF);
                        negm[ti][r] = fminf(negm[ti][r], same ? BIGF : s);
                    }
        } else {
            #pragma unroll
            for (int ti = 0; ti < 4; ti++)
                #pragma unroll
                for (int tj = 0; tj < 4; tj++)
                    #pragma unroll
                    for (int r = 0; r < 4; r++) {
                        float s = fmaf(-2.0f, acc[ti][tj][r], sqj[tj]);
                        bool same = (lbli[ti][r] == lblj[tj]);
                        bool isd  = (ti == tj) && (dr == r);
                        posm[ti][r] = fmaxf(posm[ti][r], (same && !isd) ? s : -BIGF);
                        negm[ti][r] = fminf(negm[ti][r], same ? BIGF : s);
                    }
        }
    }

    // reduce across the 16 column-lanes sharing each row; one atomic pair per row
    #pragma unroll
    for (int ti = 0; ti < 4; ti++)
        #pragma unroll
        for (int r = 0; r < 4; r++) {
            float p = posm[ti][r];
            float n = negm[ti][r];
            #pragma unroll
            for (int m = 8; m >= 1; m >>= 1) {
                p = fmaxf(p, __shfl_xor(p, m));
                n = fminf(n, __shfl_xor(n, m));
            }
            if (l15 == 0) {
                int row = i0 + wrow + ti * 16 + quad * 4 + r;
                float d2p = fmaxf(0.0f, sqi[ti][r] + p);   // no positive -> 0
                float d2n = fmaxf(0.0f, sqi[ti][r] + n);   // clamp bf16-noise negatives
                atomicMax(&posb[row], __float_as_uint(d2p));
                atomicMin(&negb[row], __float_as_uint(d2n));
            }
        }
}

__global__ __launch_bounds__(256) void tri_final(const unsigned* __restrict__ posb,
                                                 const unsigned* __restrict__ negb,
                                                 const float* __restrict__ margin,
                                                 float* __restrict__ out) {
    int r = blockIdx.x * 256 + threadIdx.x;
    float m = margin[0];
    float p  = sqrtf(__uint_as_float(posb[r]));
    float ng = sqrtf(__uint_as_float(negb[r]));
    float loss = fmaxf(p - ng + m, 0.0f) * (1.0f / (float)NROW);
    #pragma unroll
    for (int o = 32; o > 0; o >>= 1) loss += __shfl_down(loss, o);
    __shared__ float wsum[4];
    int lane = threadIdx.x & 63, wv = threadIdx.x >> 6;
    if (lane == 0) wsum[wv] = loss;
    __syncthreads();
    if (threadIdx.x == 0) atomicAdd(out, wsum[0] + wsum[1] + wsum[2] + wsum[3]);
}

extern "C" void kernel_launch(void* const* d_in, const int* in_sizes, int n_in,
                              void* d_out, int out_size, void* d_ws, size_t ws_size,
                              hipStream_t stream) {
    const float* x      = (const float*)d_in[0];
    const int*   lbl    = (const int*)d_in[1];
    const float* margin = (const float*)d_in[2];
    float* out = (float*)d_out;

    unsigned short* xbT = (unsigned short*)d_ws;                              // 2 MB
    uint2*    meta = (uint2*)((char*)d_ws + (size_t)NROW * DIM * 2);          // 64 KB
    unsigned* posb = (unsigned*)((char*)meta + NROW * 8);
    unsigned* negb = posb + NROW;

    prep_kernel<<<128, 256, 0, stream>>>(x, lbl, xbT, meta, posb, negb, out);
    tri_mfma<<<64 * JSPLIT, 256, 0, stream>>>(xbT, meta, posb, negb);
    tri_final<<<NROW / 256, 256, 0, stream>>>(posb, negb, margin, out);
}